// Round 1
// baseline (990.820 us; speedup 1.0000x reference)
//
#include <hip/hip_runtime.h>

typedef __attribute__((ext_vector_type(8))) short bf16x8;
typedef __attribute__((ext_vector_type(4))) float f32x4;

#define MFMA16(a, b, c) __builtin_amdgcn_mfma_f32_16x16x32_bf16(a, b, c, 0, 0, 0)

static __device__ __forceinline__ short f2bf(float f) {
    union { float f; unsigned u; } x; x.f = f;
    unsigned r = x.u + 0x7FFFu + ((x.u >> 16) & 1u);
    return (short)(r >> 16);
}

// ---------- weight transpose + convert: in (K,N) f32 -> out (N,K) bf16 ----------
__global__ void convT_kernel(const float* __restrict__ in, short* __restrict__ out, int K, int N) {
    int idx = blockIdx.x * 256 + threadIdx.x;
    if (idx < K * N) {
        int k = idx % K, n = idx / K;
        out[idx] = f2bf(in[(size_t)k * N + n]);
    }
}

// ---------- patch embed: x (32,3,224,224) f32 -> out (100352,128) f32 ----------
__global__ __launch_bounds__(256) void patch_kernel(const float* __restrict__ x,
                                                    const float* __restrict__ w,
                                                    const float* __restrict__ bias,
                                                    float* __restrict__ out) {
    __shared__ float s_in[2][48];
    const int tid = threadIdx.x;
    const int half = tid >> 7, c = tid & 127;
    const int t = blockIdx.x * 2 + half;
    const int b = t / 3136, rem = t - b * 3136;
    const int hp = rem / 56, wp = rem - hp * 56;
    if (c < 48) {
        int cin = c >> 4, py = (c >> 2) & 3, px = c & 3;
        s_in[half][c] = x[((size_t)(b * 3 + cin) * 224 + hp * 4 + py) * 224 + wp * 4 + px];
    }
    __syncthreads();
    float acc = bias[c];
#pragma unroll
    for (int k = 0; k < 48; ++k) acc += s_in[half][k] * w[k * 128 + c];
    out[(size_t)t * 128 + c] = acc;
}

// ---------- LayerNorm: x (TOK,128) f32 -> out (TOK,128) bf16 ----------
__global__ __launch_bounds__(256) void ln_kernel(const float* __restrict__ x,
                                                 const float* __restrict__ g,
                                                 const float* __restrict__ bta,
                                                 short* __restrict__ out) {
    const int wid = threadIdx.x >> 6, lane = threadIdx.x & 63;
    const size_t t = (size_t)blockIdx.x * 4 + wid;
    const float* xr = x + t * 128;
    float v0 = xr[lane], v1 = xr[lane + 64];
    float s = v0 + v1;
#pragma unroll
    for (int o = 32; o > 0; o >>= 1) s += __shfl_xor(s, o);
    float m = s * (1.f / 128.f);
    float d0 = v0 - m, d1 = v1 - m;
    float q = d0 * d0 + d1 * d1;
#pragma unroll
    for (int o = 32; o > 0; o >>= 1) q += __shfl_xor(q, o);
    float r = rsqrtf(q * (1.f / 128.f) + 1e-5f);
    out[t * 128 + lane] = f2bf(d0 * r * g[lane] + bta[lane]);
    out[t * 128 + lane + 64] = f2bf(d1 * r * g[lane + 64] + bta[lane + 64]);
}

// ---------- fused window attention ----------
// block = (b, head, window); 4 waves, 256 threads; 64 KB LDS
template <int SHIFTED>
__global__ __launch_bounds__(256) void attn_kernel(const short* __restrict__ xn,
                                                   const short* __restrict__ wqkvT,
                                                   const float* __restrict__ pos,
                                                   short* __restrict__ aout) {
    __shared__ short smem[32768];               // 64 KB
    short* s_x = smem;                          // 64x128 bf16 (later dots f32 64x64)
    short* s_q = smem + 8192;                   // 64x128 bf16 (later P bf16 64x64)
    short* s_k = smem + 16384;                  // 64x128 bf16
    short* s_vT = smem + 24576;                 // 128x64 bf16 (V transposed)
    float* s_dots = (float*)smem;
    short* s_p = smem + 8192;

    const int tid = threadIdx.x;
    const int wid = tid >> 6, lane = tid & 63;
    const int l15 = lane & 15, l4 = lane >> 4, klo = l4 * 8;
    const int bid = blockIdx.x;
    const int win = bid & 63, head = (bid >> 6) & 3, b = bid >> 8;
    const int wh = win >> 3, wwin = win & 7;

    // load X window (pad rows 49..63 with zero)
    for (int e = tid * 8; e < 64 * 128; e += 2048) {
        int row = e >> 7, col = e & 127;
        bf16x8 v = {0, 0, 0, 0, 0, 0, 0, 0};
        if (row < 49) {
            int wi = row / 7, wj = row - wi * 7;
            int hh = wh * 7 + wi, ww = wwin * 7 + wj;
            if (SHIFTED) { hh += 3; if (hh >= 56) hh -= 56; ww += 3; if (ww >= 56) ww -= 56; }
            int t = (b * 56 + hh) * 56 + ww;
            v = *(const bf16x8*)(xn + (size_t)t * 128 + col);
        }
        *(bf16x8*)(s_x + row * 128 + col) = v;
    }
    __syncthreads();

    const f32x4 zero4 = {0.f, 0.f, 0.f, 0.f};

    // projections: q, k, v  (each wave computes a 32-wide N slice)
    for (int pr = 0; pr < 3; ++pr) {
        f32x4 acc[4][2];
#pragma unroll
        for (int m = 0; m < 4; ++m)
#pragma unroll
            for (int n = 0; n < 2; ++n) acc[m][n] = zero4;
        const short* Bb = wqkvT + (size_t)(pr * 512 + head * 128 + wid * 32) * 128;
#pragma unroll
        for (int k0 = 0; k0 < 4; ++k0) {
            bf16x8 a[4], bfr[2];
#pragma unroll
            for (int m = 0; m < 4; ++m)
                a[m] = *(const bf16x8*)(s_x + (m * 16 + l15) * 128 + k0 * 32 + klo);
#pragma unroll
            for (int n = 0; n < 2; ++n)
                bfr[n] = *(const bf16x8*)(Bb + (size_t)(n * 16 + l15) * 128 + k0 * 32 + klo);
#pragma unroll
            for (int m = 0; m < 4; ++m)
#pragma unroll
                for (int n = 0; n < 2; ++n) acc[m][n] = MFMA16(a[m], bfr[n], acc[m][n]);
        }
        if (pr == 2) {
#pragma unroll
            for (int m = 0; m < 4; ++m)
#pragma unroll
                for (int n = 0; n < 2; ++n)
#pragma unroll
                    for (int r = 0; r < 4; ++r)
                        s_vT[(wid * 32 + n * 16 + l15) * 64 + m * 16 + l4 * 4 + r] = f2bf(acc[m][n][r]);
        } else {
            short* dst = (pr == 0) ? s_q : s_k;
#pragma unroll
            for (int m = 0; m < 4; ++m)
#pragma unroll
                for (int n = 0; n < 2; ++n)
#pragma unroll
                    for (int r = 0; r < 4; ++r)
                        dst[(m * 16 + l4 * 4 + r) * 128 + wid * 32 + n * 16 + l15] = f2bf(acc[m][n][r]);
        }
    }
    __syncthreads();

    // dots = Q @ K^T ; each wave computes 16 key-columns, all 64 rows
    {
        f32x4 acc[4];
#pragma unroll
        for (int m = 0; m < 4; ++m) acc[m] = zero4;
#pragma unroll
        for (int k0 = 0; k0 < 4; ++k0) {
            bf16x8 bfr = *(const bf16x8*)(s_k + (wid * 16 + l15) * 128 + k0 * 32 + klo);
#pragma unroll
            for (int m = 0; m < 4; ++m) {
                bf16x8 a = *(const bf16x8*)(s_q + (m * 16 + l15) * 128 + k0 * 32 + klo);
                acc[m] = MFMA16(a, bfr, acc[m]);
            }
        }
#pragma unroll
        for (int m = 0; m < 4; ++m)
#pragma unroll
            for (int r = 0; r < 4; ++r)
                s_dots[(m * 16 + l4 * 4 + r) * 64 + wid * 16 + l15] = acc[m][r];
    }
    __syncthreads();

    // softmax over each row (scale + pos bias + shift masks); P -> bf16
    {
        const int row = tid >> 2, col0 = (tid & 3) * 16;
        const float SC = 0.08838834764831845f;
        int qi = row / 7, qj = row - qi * 7;
        bool qr4 = (qi >= 4), qc4 = (qj >= 4);
        float v[16];
        float mx = -3.0e38f;
#pragma unroll
        for (int c = 0; c < 16; ++c) {
            int col = col0 + c;
            float d = s_dots[row * 64 + col] * SC;
            if (col >= 49) {
                d = -1e9f;
            } else if (row < 49) {
                int ki = col / 7, kj = col - ki * 7;
                d += pos[(ki - qi + 6) * 13 + (kj - qj + 6)];
                if (SHIFTED) {
                    if (wh == 7 && (qr4 != (ki >= 4))) d -= 1e9f;
                    if (wwin == 7 && (qc4 != (kj >= 4))) d -= 1e9f;
                }
            }
            v[c] = d;
            mx = fmaxf(mx, d);
        }
        mx = fmaxf(mx, __shfl_xor(mx, 1));
        mx = fmaxf(mx, __shfl_xor(mx, 2));
        float sum = 0.f;
#pragma unroll
        for (int c = 0; c < 16; ++c) { v[c] = __expf(v[c] - mx); sum += v[c]; }
        sum += __shfl_xor(sum, 1);
        sum += __shfl_xor(sum, 2);
        float inv = 1.f / sum;
#pragma unroll
        for (int c = 0; c < 16; ++c) s_p[row * 64 + col0 + c] = f2bf(v[c] * inv);
    }
    __syncthreads();

    // out = P @ V ; each wave computes a 32-wide slice of head_dim
    {
        f32x4 acc[4][2];
#pragma unroll
        for (int m = 0; m < 4; ++m)
#pragma unroll
            for (int n = 0; n < 2; ++n) acc[m][n] = zero4;
#pragma unroll
        for (int k0 = 0; k0 < 2; ++k0) {
            bf16x8 a[4], bfr[2];
#pragma unroll
            for (int m = 0; m < 4; ++m)
                a[m] = *(const bf16x8*)(s_p + (m * 16 + l15) * 64 + k0 * 32 + klo);
#pragma unroll
            for (int n = 0; n < 2; ++n)
                bfr[n] = *(const bf16x8*)(s_vT + (wid * 32 + n * 16 + l15) * 64 + k0 * 32 + klo);
#pragma unroll
            for (int m = 0; m < 4; ++m)
#pragma unroll
                for (int n = 0; n < 2; ++n) acc[m][n] = MFMA16(a[m], bfr[n], acc[m][n]);
        }
#pragma unroll
        for (int m = 0; m < 4; ++m) {
#pragma unroll
            for (int r = 0; r < 4; ++r) {
                int rl = m * 16 + l4 * 4 + r;
                if (rl < 49) {
                    int wi = rl / 7, wj = rl - wi * 7;
                    int hh = wh * 7 + wi, ww = wwin * 7 + wj;
                    if (SHIFTED) { hh += 3; if (hh >= 56) hh -= 56; ww += 3; if (ww >= 56) ww -= 56; }
                    size_t t = (size_t)(b * 56 + hh) * 56 + ww;
#pragma unroll
                    for (int n = 0; n < 2; ++n)
                        aout[t * 512 + head * 128 + wid * 32 + n * 16 + l15] = f2bf(acc[m][n][r]);
                }
            }
        }
    }
}

// ---------- generic GEMM: out[M,Ntot] = A[M,K](bf16) @ BT[Ntot,K]^T + bias (+gelu / +resid) ----------
template <int K, bool TGELU, bool TRESID, bool TOBF16>
__global__ __launch_bounds__(256) void gemm_kernel(const short* __restrict__ A,
                                                   const short* __restrict__ BT,
                                                   const float* __restrict__ bias,
                                                   const float* __restrict__ resid,
                                                   void* __restrict__ outp,
                                                   int Ntot) {
    __shared__ short s_a[64 * 64];
    const int tid = threadIdx.x, wid = tid >> 6, lane = tid & 63;
    const int l15 = lane & 15, l4 = lane >> 4, klo = l4 * 8;
    const int m0 = blockIdx.x * 64;
    const int nb0 = blockIdx.y * 128;

    const f32x4 zero4 = {0.f, 0.f, 0.f, 0.f};
    f32x4 acc[4][2];
#pragma unroll
    for (int m = 0; m < 4; ++m)
#pragma unroll
        for (int n = 0; n < 2; ++n) acc[m][n] = zero4;

    for (int kc = 0; kc < K / 64; ++kc) {
#pragma unroll
        for (int it = 0; it < 2; ++it) {
            int e = it * 2048 + tid * 8;
            int row = e >> 6, col = e & 63;
            *(bf16x8*)(s_a + row * 64 + col) =
                *(const bf16x8*)(A + (size_t)(m0 + row) * K + kc * 64 + col);
        }
        __syncthreads();
#pragma unroll
        for (int ks = 0; ks < 2; ++ks) {
            int k0 = ks * 32;
            bf16x8 a[4], bfr[2];
#pragma unroll
            for (int m = 0; m < 4; ++m)
                a[m] = *(const bf16x8*)(s_a + (m * 16 + l15) * 64 + k0 + klo);
#pragma unroll
            for (int n = 0; n < 2; ++n)
                bfr[n] = *(const bf16x8*)(BT + (size_t)(nb0 + wid * 32 + n * 16 + l15) * K + kc * 64 + k0 + klo);
#pragma unroll
            for (int m = 0; m < 4; ++m)
#pragma unroll
                for (int n = 0; n < 2; ++n) acc[m][n] = MFMA16(a[m], bfr[n], acc[m][n]);
        }
        __syncthreads();
    }

#pragma unroll
    for (int n = 0; n < 2; ++n) {
        int col = nb0 + wid * 32 + n * 16 + l15;
        float bv = bias[col];
#pragma unroll
        for (int m = 0; m < 4; ++m) {
#pragma unroll
            for (int r = 0; r < 4; ++r) {
                int row = m0 + m * 16 + l4 * 4 + r;
                float v2 = acc[m][n][r] + bv;
                if (TGELU) v2 = 0.5f * v2 * (1.f + erff(v2 * 0.70710678118f));
                if (TRESID) v2 += resid[(size_t)row * Ntot + col];
                if (TOBF16) ((short*)outp)[(size_t)row * Ntot + col] = f2bf(v2);
                else ((float*)outp)[(size_t)row * Ntot + col] = v2;
            }
        }
    }
}

extern "C" void kernel_launch(void* const* d_in, const int* in_sizes, int n_in,
                              void* d_out, int out_size, void* d_ws, size_t ws_size,
                              hipStream_t stream) {
    const float* x = (const float*)d_in[0];
    const float* w_pe = (const float*)d_in[1];
    const float* b_pe = (const float*)d_in[2];
    const float* P[24];
    for (int i = 0; i < 24; ++i) P[i] = (const float*)d_in[3 + i];
    // per layer s (0=a,1=b): [s*12 + 0..11] = ga1, be1, w_qkv, pos, w_o, b_o, ga2, be2, w_m1, b_m1, w_m2, b_m2

    float* out = (float*)d_out;
    const size_t TOK = 100352;

    short* xn = (short*)d_ws;          // TOK*128 bf16
    short* abuf = xn + TOK * 128;      // TOK*512 bf16 (attn_out, then mlp hidden)
    short* wp = abuf + TOK * 512;
    short* wT[8];
    for (int s = 0; s < 2; ++s) {
        wT[s * 4 + 0] = wp; wp += 196608;   // qkv^T (1536x128)
        wT[s * 4 + 1] = wp; wp += 65536;    // w_o^T (128x512)
        wT[s * 4 + 2] = wp; wp += 65536;    // w_m1^T (512x128)
        wT[s * 4 + 3] = wp; wp += 65536;    // w_m2^T (128x512)
    }

    for (int s = 0; s < 2; ++s) {
        convT_kernel<<<768, 256, 0, stream>>>(P[s * 12 + 2], wT[s * 4 + 0], 128, 1536);
        convT_kernel<<<256, 256, 0, stream>>>(P[s * 12 + 4], wT[s * 4 + 1], 512, 128);
        convT_kernel<<<256, 256, 0, stream>>>(P[s * 12 + 8], wT[s * 4 + 2], 128, 512);
        convT_kernel<<<256, 256, 0, stream>>>(P[s * 12 + 10], wT[s * 4 + 3], 512, 128);
    }

    patch_kernel<<<50176, 256, 0, stream>>>(x, w_pe, b_pe, out);

    for (int s = 0; s < 2; ++s) {
        ln_kernel<<<25088, 256, 0, stream>>>(out, P[s * 12 + 0], P[s * 12 + 1], xn);
        if (s == 0)
            attn_kernel<0><<<8192, 256, 0, stream>>>(xn, wT[0], P[0 * 12 + 3], abuf);
        else
            attn_kernel<1><<<8192, 256, 0, stream>>>(xn, wT[4], P[1 * 12 + 3], abuf);
        gemm_kernel<512, false, true, false><<<dim3(1568, 1), 256, 0, stream>>>(
            abuf, wT[s * 4 + 1], P[s * 12 + 5], out, out, 128);
        ln_kernel<<<25088, 256, 0, stream>>>(out, P[s * 12 + 6], P[s * 12 + 7], xn);
        gemm_kernel<128, true, false, true><<<dim3(1568, 4), 256, 0, stream>>>(
            xn, wT[s * 4 + 2], P[s * 12 + 9], nullptr, abuf, 512);
        gemm_kernel<512, false, true, false><<<dim3(1568, 1), 256, 0, stream>>>(
            abuf, wT[s * 4 + 3], P[s * 12 + 11], out, out, 128);
    }
}

// Round 2
// 711.286 us; speedup vs baseline: 1.3930x; 1.3930x over previous
//
#include <hip/hip_runtime.h>

typedef __attribute__((ext_vector_type(8))) short bf16x8;
typedef __attribute__((ext_vector_type(4))) short bf16x4;
typedef __attribute__((ext_vector_type(4))) float f32x4;

#define MFMA16(a, b, c) __builtin_amdgcn_mfma_f32_16x16x32_bf16(a, b, c, 0, 0, 0)

static __device__ __forceinline__ short f2bf(float f) {
    union { float f; unsigned u; } x; x.f = f;
    unsigned r = x.u + 0x7FFFu + ((x.u >> 16) & 1u);
    return (short)(r >> 16);
}

static __device__ __forceinline__ void gload16(const void* g, void* l) {
    __builtin_amdgcn_global_load_lds((const __attribute__((address_space(1))) void*)g,
                                     (__attribute__((address_space(3))) void*)l, 16, 0, 0);
}

// ---------- weight transpose + convert: in (K,N) f32 -> out (N,K) bf16 ----------
__global__ void convT_kernel(const float* __restrict__ in, short* __restrict__ out, int K, int N) {
    int idx = blockIdx.x * 256 + threadIdx.x;
    if (idx < K * N) {
        int k = idx % K, n = idx / K;
        out[idx] = f2bf(in[(size_t)k * N + n]);
    }
}

// ---------- bias+mask table: tab[5][64][64] ----------
__global__ void tabgen_kernel(const float* __restrict__ pos_a, const float* __restrict__ pos_b,
                              float* __restrict__ tab) {
    int v = blockIdx.x;
    const float* pos = (v == 0) ? pos_a : pos_b;
    for (int e = threadIdx.x; e < 4096; e += 256) {
        int row = e >> 6, key = e & 63;
        float val;
        if (key >= 49) val = -1e9f;
        else if (row >= 49) val = 0.f;
        else {
            int qi = row / 7, qj = row - qi * 7, ki = key / 7, kj = key - ki * 7;
            val = pos[(ki - qi + 6) * 13 + (kj - qj + 6)];
            if (v >= 1) {
                bool wh7 = (v - 1) & 2, ww7 = (v - 1) & 1;
                if (wh7 && ((qi >= 4) != (ki >= 4))) val += -1e9f;
                if (ww7 && ((qj >= 4) != (kj >= 4))) val += -1e9f;
            }
        }
        tab[v * 4096 + e] = val;
    }
}

// ---------- patch embed ----------
__global__ __launch_bounds__(256) void patch_kernel(const float* __restrict__ x,
                                                    const float* __restrict__ w,
                                                    const float* __restrict__ bias,
                                                    float* __restrict__ out) {
    __shared__ float s_in[2][48];
    const int tid = threadIdx.x;
    const int half = tid >> 7, c = tid & 127;
    const int t = blockIdx.x * 2 + half;
    const int b = t / 3136, rem = t - b * 3136;
    const int hp = rem / 56, wp = rem - hp * 56;
    if (c < 48) {
        int cin = c >> 4, py = (c >> 2) & 3, px = c & 3;
        s_in[half][c] = x[((size_t)(b * 3 + cin) * 224 + hp * 4 + py) * 224 + wp * 4 + px];
    }
    __syncthreads();
    float acc = bias[c];
#pragma unroll
    for (int k = 0; k < 48; ++k) acc += s_in[half][k] * w[k * 128 + c];
    out[(size_t)t * 128 + c] = acc;
}

// ---------- LayerNorm: x (TOK,128) f32 -> out bf16 ----------
__global__ __launch_bounds__(256) void ln_kernel(const float* __restrict__ x,
                                                 const float* __restrict__ g,
                                                 const float* __restrict__ bta,
                                                 short* __restrict__ out) {
    typedef struct { float x, y; } f2;
    const int wid = threadIdx.x >> 6, lane = threadIdx.x & 63;
    const size_t t = (size_t)blockIdx.x * 4 + wid;
    f2 v = ((const f2*)(x + t * 128))[lane];
    float s = v.x + v.y;
#pragma unroll
    for (int o = 32; o > 0; o >>= 1) s += __shfl_xor(s, o);
    float m = s * (1.f / 128.f);
    float d0 = v.x - m, d1 = v.y - m;
    float q = d0 * d0 + d1 * d1;
#pragma unroll
    for (int o = 32; o > 0; o >>= 1) q += __shfl_xor(q, o);
    float r = rsqrtf(q * (1.f / 128.f) + 1e-5f);
    f2 gg = ((const f2*)g)[lane], bb = ((const f2*)bta)[lane];
    unsigned lo = (unsigned short)f2bf(d0 * r * gg.x + bb.x);
    unsigned hi = (unsigned short)f2bf(d1 * r * gg.y + bb.y);
    ((unsigned*)out)[t * 64 + lane] = lo | (hi << 16);
}

// ---------- fused window attention (swizzled LDS, in-register softmax) ----------
template <int SHIFTED>
__global__ __launch_bounds__(256) void attn_kernel(const short* __restrict__ xn,
                                                   const short* __restrict__ wqkvT,
                                                   const float* __restrict__ tab,
                                                   const short* __restrict__ zpad,
                                                   short* __restrict__ aout) {
    __shared__ short smem[32768];               // 64 KB
    short* s_x = smem;                          // 64 x 256B (swizzled)
    short* s_q = smem + 8192;                   // 64 x 256B
    short* s_k = smem + 16384;                  // 64 x 256B
    short* s_vT = smem + 24576;                 // 128 x 128B (V^T)
    short* s_p = smem;                          // overlays s_x, 64 x 128B

    const int tid = threadIdx.x;
    const int wid = tid >> 6, lane = tid & 63;
    const int l15 = lane & 15, l4 = lane >> 4, klo = l4 * 8;
    const int bid = blockIdx.x;
    const int win = bid & 63, head = (bid >> 6) & 3, b = bid >> 8;
    const int wh = win >> 3, ww = win & 7;

    // ---- stage X window into swizzled s_x via global_load_lds ----
#pragma unroll
    for (int it = 0; it < 4; ++it) {
        int slot = it * 256 + tid;
        int row = slot >> 4, scol = slot & 15;
        int colb = (scol * 16) ^ ((row & 7) << 4);
        const char* g;
        if (row < 49) {
            int wi = row / 7, wj = row - wi * 7;
            int hh = wh * 7 + wi, wp = ww * 7 + wj;
            if (SHIFTED) { hh += 3; if (hh >= 56) hh -= 56; wp += 3; if (wp >= 56) wp -= 56; }
            int t = (b * 56 + hh) * 56 + wp;
            g = (const char*)(xn + (size_t)t * 128) + colb;
        } else {
            g = (const char*)zpad + colb;
        }
        gload16(g, (char*)smem + (it * 256 + wid * 64) * 16);
    }
    __syncthreads();

    const f32x4 zero4 = {0.f, 0.f, 0.f, 0.f};

    // ---- Q,K projections (swapped: mfma(W,X) -> packed col stores) ----
#pragma unroll
    for (int pr = 0; pr < 2; ++pr) {
        const short* Wb = wqkvT + (size_t)(pr * 512 + head * 128) * 128;
        f32x4 acc[2][4];
#pragma unroll
        for (int mw = 0; mw < 2; ++mw)
#pragma unroll
            for (int j = 0; j < 4; ++j) acc[mw][j] = zero4;
#pragma unroll
        for (int k0 = 0; k0 < 4; ++k0) {
            bf16x8 aw[2], bx[4];
#pragma unroll
            for (int mw = 0; mw < 2; ++mw)
                aw[mw] = *(const bf16x8*)(Wb + (size_t)(wid * 32 + mw * 16 + l15) * 128 + k0 * 32 + klo);
#pragma unroll
            for (int j = 0; j < 4; ++j) {
                int row = j * 16 + l15;
                bx[j] = *(const bf16x8*)((const char*)s_x + row * 256 + ((k0 * 64 + l4 * 16) ^ ((row & 7) << 4)));
            }
#pragma unroll
            for (int mw = 0; mw < 2; ++mw)
#pragma unroll
                for (int j = 0; j < 4; ++j) acc[mw][j] = MFMA16(aw[mw], bx[j], acc[mw][j]);
        }
        short* dst = pr ? s_k : s_q;
#pragma unroll
        for (int mw = 0; mw < 2; ++mw)
#pragma unroll
            for (int j = 0; j < 4; ++j) {
                bf16x4 pv;
#pragma unroll
                for (int r = 0; r < 4; ++r) pv[r] = f2bf(acc[mw][j][r]);
                int row = j * 16 + l15;
                int colb = wid * 64 + mw * 32 + l4 * 8;
                *(bf16x4*)((char*)dst + row * 256 + (colb ^ ((row & 7) << 4))) = pv;
            }
    }
    // ---- V projection (normal: mfma(X,W) -> packed stores into V^T) ----
    {
        const short* Wb = wqkvT + (size_t)(1024 + head * 128) * 128;
        f32x4 acc[4][2];
#pragma unroll
        for (int m = 0; m < 4; ++m)
#pragma unroll
            for (int n = 0; n < 2; ++n) acc[m][n] = zero4;
#pragma unroll
        for (int k0 = 0; k0 < 4; ++k0) {
            bf16x8 ax[4], bw[2];
#pragma unroll
            for (int m = 0; m < 4; ++m) {
                int row = m * 16 + l15;
                ax[m] = *(const bf16x8*)((const char*)s_x + row * 256 + ((k0 * 64 + l4 * 16) ^ ((row & 7) << 4)));
            }
#pragma unroll
            for (int n = 0; n < 2; ++n)
                bw[n] = *(const bf16x8*)(Wb + (size_t)(wid * 32 + n * 16 + l15) * 128 + k0 * 32 + klo);
#pragma unroll
            for (int m = 0; m < 4; ++m)
#pragma unroll
                for (int n = 0; n < 2; ++n) acc[m][n] = MFMA16(ax[m], bw[n], acc[m][n]);
        }
#pragma unroll
        for (int m = 0; m < 4; ++m)
#pragma unroll
            for (int n = 0; n < 2; ++n) {
                bf16x4 pv;
#pragma unroll
                for (int r = 0; r < 4; ++r) pv[r] = f2bf(acc[m][n][r]);
                int hd = wid * 32 + n * 16 + l15;
                int colb = m * 32 + l4 * 8;
                *(bf16x4*)((char*)s_vT + hd * 128 + (colb ^ ((hd & 7) << 4))) = pv;
            }
    }
    __syncthreads();

    // ---- dots^T = mfma(K,Q): lane holds one query-row's 16 scores ----
    const int qrow = wid * 16 + l15;
    f32x4 dt[4];
#pragma unroll
    for (int m = 0; m < 4; ++m) dt[m] = zero4;
#pragma unroll
    for (int k0 = 0; k0 < 4; ++k0) {
        bf16x8 bq = *(const bf16x8*)((const char*)s_q + qrow * 256 + ((k0 * 64 + l4 * 16) ^ ((qrow & 7) << 4)));
#pragma unroll
        for (int m = 0; m < 4; ++m) {
            int krow = m * 16 + l15;
            bf16x8 ak = *(const bf16x8*)((const char*)s_k + krow * 256 + ((k0 * 64 + l4 * 16) ^ ((krow & 7) << 4)));
            dt[m] = MFMA16(ak, bq, dt[m]);
        }
    }

    // ---- in-register softmax (reduce across the 4 lanes sharing l15) ----
    const int variant = SHIFTED ? (1 + ((wh == 7) ? 2 : 0) + ((ww == 7) ? 1 : 0)) : 0;
    const float* tv = tab + variant * 4096 + qrow * 64;
    const float SC = 0.08838834764831845f;
    float p[4][4];
    float mx = -3.0e38f;
#pragma unroll
    for (int m = 0; m < 4; ++m) {
        f32x4 tb = *(const f32x4*)(tv + m * 16 + l4 * 4);
#pragma unroll
        for (int r = 0; r < 4; ++r) {
            float d = dt[m][r] * SC + tb[r];
            p[m][r] = d;
            mx = fmaxf(mx, d);
        }
    }
    mx = fmaxf(mx, __shfl_xor(mx, 16));
    mx = fmaxf(mx, __shfl_xor(mx, 32));
    float sum = 0.f;
#pragma unroll
    for (int m = 0; m < 4; ++m)
#pragma unroll
        for (int r = 0; r < 4; ++r) { p[m][r] = __expf(p[m][r] - mx); sum += p[m][r]; }
    sum += __shfl_xor(sum, 16);
    sum += __shfl_xor(sum, 32);
    float inv = 1.f / sum;
#pragma unroll
    for (int m = 0; m < 4; ++m) {
        bf16x4 pv;
#pragma unroll
        for (int r = 0; r < 4; ++r) pv[r] = f2bf(p[m][r] * inv);
        *(bf16x4*)((char*)s_p + qrow * 128 + ((m * 32 + l4 * 8) ^ ((qrow & 7) << 4))) = pv;
    }
    __syncthreads();

    // ---- out = P @ V ----
    f32x4 o[4][2];
#pragma unroll
    for (int m = 0; m < 4; ++m)
#pragma unroll
        for (int n = 0; n < 2; ++n) o[m][n] = zero4;
#pragma unroll
    for (int k0 = 0; k0 < 2; ++k0) {
        bf16x8 ap[4], bv[2];
#pragma unroll
        for (int m = 0; m < 4; ++m) {
            int row = m * 16 + l15;
            ap[m] = *(const bf16x8*)((const char*)s_p + row * 128 + ((k0 * 64 + l4 * 16) ^ ((row & 7) << 4)));
        }
#pragma unroll
        for (int n = 0; n < 2; ++n) {
            int hd = wid * 32 + n * 16 + l15;
            bv[n] = *(const bf16x8*)((const char*)s_vT + hd * 128 + ((k0 * 64 + l4 * 16) ^ ((hd & 7) << 4)));
        }
#pragma unroll
        for (int m = 0; m < 4; ++m)
#pragma unroll
            for (int n = 0; n < 2; ++n) o[m][n] = MFMA16(ap[m], bv[n], o[m][n]);
    }
#pragma unroll
    for (int m = 0; m < 4; ++m) {
#pragma unroll
        for (int r = 0; r < 4; ++r) {
            int rl = m * 16 + l4 * 4 + r;
            if (rl < 49) {
                int wi = rl / 7, wj = rl - wi * 7;
                int hh = wh * 7 + wi, wp = ww * 7 + wj;
                if (SHIFTED) { hh += 3; if (hh >= 56) hh -= 56; wp += 3; if (wp >= 56) wp -= 56; }
                size_t t = (size_t)(b * 56 + hh) * 56 + wp;
                aout[t * 512 + head * 128 + wid * 32 + l15] = f2bf(o[m][0][r]);
                aout[t * 512 + head * 128 + wid * 32 + 16 + l15] = f2bf(o[m][1][r]);
            }
        }
    }
}

// ---------- GEMM: out[M,Ntot] = A[M,K] @ BT[Ntot,K]^T + bias (+gelu/+resid) ----------
template <int K, bool TGELU, bool TRESID, bool TOBF16>
__global__ __launch_bounds__(256) void gemm_kernel(const short* __restrict__ A,
                                                   const short* __restrict__ BT,
                                                   const float* __restrict__ bias,
                                                   const float* __restrict__ resid,
                                                   void* __restrict__ outp,
                                                   int Ntot) {
    __shared__ short s_a[64 * 64];  // 64 rows x 128B, swizzled
    const int tid = threadIdx.x, wid = tid >> 6, lane = tid & 63;
    const int l15 = lane & 15, l4 = lane >> 4, klo = l4 * 8;
    const int m0 = blockIdx.x * 64;
    const int nb0 = blockIdx.y * 128;

    const f32x4 zero4 = {0.f, 0.f, 0.f, 0.f};
    f32x4 acc[4][2];
#pragma unroll
    for (int m = 0; m < 4; ++m)
#pragma unroll
        for (int n = 0; n < 2; ++n) acc[m][n] = zero4;

    for (int kc = 0; kc < K / 64; ++kc) {
#pragma unroll
        for (int it = 0; it < 2; ++it) {
            int slot = it * 256 + tid;
            int row = slot >> 3, scol = slot & 7;
            int colb = (scol * 16) ^ ((row & 7) << 4);
            const char* g = (const char*)(A + (size_t)(m0 + row) * K + kc * 64) + colb;
            gload16(g, (char*)s_a + (it * 256 + wid * 64) * 16);
        }
        __syncthreads();
#pragma unroll
        for (int ks = 0; ks < 2; ++ks) {
            bf16x8 a[4], bfr[2];
#pragma unroll
            for (int m = 0; m < 4; ++m) {
                int row = m * 16 + l15;
                a[m] = *(const bf16x8*)((const char*)s_a + row * 128 + ((ks * 64 + l4 * 16) ^ ((row & 7) << 4)));
            }
#pragma unroll
            for (int n = 0; n < 2; ++n)
                bfr[n] = *(const bf16x8*)(BT + (size_t)(nb0 + wid * 32 + n * 16 + l15) * K + kc * 64 + ks * 32 + klo);
#pragma unroll
            for (int m = 0; m < 4; ++m)
#pragma unroll
                for (int n = 0; n < 2; ++n) acc[m][n] = MFMA16(a[m], bfr[n], acc[m][n]);
        }
        __syncthreads();
    }

#pragma unroll
    for (int n = 0; n < 2; ++n) {
        int col = nb0 + wid * 32 + n * 16 + l15;
        float bv = bias[col];
#pragma unroll
        for (int m = 0; m < 4; ++m) {
#pragma unroll
            for (int r = 0; r < 4; ++r) {
                int row = m0 + m * 16 + l4 * 4 + r;
                float v2 = acc[m][n][r] + bv;
                if (TGELU) v2 = 0.5f * v2 * (1.f + erff(v2 * 0.70710678118f));
                if (TRESID) v2 += resid[(size_t)row * Ntot + col];
                if (TOBF16) ((short*)outp)[(size_t)row * Ntot + col] = f2bf(v2);
                else ((float*)outp)[(size_t)row * Ntot + col] = v2;
            }
        }
    }
}

extern "C" void kernel_launch(void* const* d_in, const int* in_sizes, int n_in,
                              void* d_out, int out_size, void* d_ws, size_t ws_size,
                              hipStream_t stream) {
    const float* x = (const float*)d_in[0];
    const float* w_pe = (const float*)d_in[1];
    const float* b_pe = (const float*)d_in[2];
    const float* P[24];
    for (int i = 0; i < 24; ++i) P[i] = (const float*)d_in[3 + i];
    // per layer s: [s*12+0..11] = ga1, be1, w_qkv, pos, w_o, b_o, ga2, be2, w_m1, b_m1, w_m2, b_m2

    float* out = (float*)d_out;
    const size_t TOK = 100352;

    short* xn = (short*)d_ws;          // TOK*128 bf16
    short* abuf = xn + TOK * 128;      // TOK*512 bf16
    short* wqkv = abuf + TOK * 512;    // 1536x128
    short* wo = wqkv + 196608;         // 128x512
    short* wm1 = wo + 65536;           // 512x128
    short* wm2 = wm1 + 65536;          // 128x512
    float* tab = (float*)(wm2 + 65536);  // 5*4096 f32
    short* zpad = (short*)(tab + 5 * 4096);  // 256B zeros

    hipMemsetAsync(zpad, 0, 256, stream);
    tabgen_kernel<<<5, 256, 0, stream>>>(P[3], P[15], tab);

    patch_kernel<<<50176, 256, 0, stream>>>(x, w_pe, b_pe, out);

    for (int s = 0; s < 2; ++s) {
        convT_kernel<<<768, 256, 0, stream>>>(P[s * 12 + 2], wqkv, 128, 1536);
        convT_kernel<<<256, 256, 0, stream>>>(P[s * 12 + 4], wo, 512, 128);
        convT_kernel<<<256, 256, 0, stream>>>(P[s * 12 + 8], wm1, 128, 512);
        convT_kernel<<<256, 256, 0, stream>>>(P[s * 12 + 10], wm2, 512, 128);

        ln_kernel<<<25088, 256, 0, stream>>>(out, P[s * 12 + 0], P[s * 12 + 1], xn);
        if (s == 0)
            attn_kernel<0><<<8192, 256, 0, stream>>>(xn, wqkv, tab, zpad, abuf);
        else
            attn_kernel<1><<<8192, 256, 0, stream>>>(xn, wqkv, tab, zpad, abuf);
        gemm_kernel<512, false, true, false><<<dim3(1568, 1), 256, 0, stream>>>(
            abuf, wo, P[s * 12 + 5], out, out, 128);
        ln_kernel<<<25088, 256, 0, stream>>>(out, P[s * 12 + 6], P[s * 12 + 7], xn);
        gemm_kernel<128, true, false, true><<<dim3(1568, 4), 256, 0, stream>>>(
            xn, wm1, P[s * 12 + 9], nullptr, abuf, 512);
        gemm_kernel<512, false, true, false><<<dim3(1568, 1), 256, 0, stream>>>(
            abuf, wm2, P[s * 12 + 11], out, out, 128);
    }
}

// Round 3
// 624.170 us; speedup vs baseline: 1.5874x; 1.1396x over previous
//
#include <hip/hip_runtime.h>

typedef __attribute__((ext_vector_type(8))) short bf16x8;
typedef __attribute__((ext_vector_type(4))) short bf16x4;
typedef __attribute__((ext_vector_type(4))) float f32x4;

#define MFMA16(a, b, c) __builtin_amdgcn_mfma_f32_16x16x32_bf16(a, b, c, 0, 0, 0)

static __device__ __forceinline__ short f2bf(float f) {
    union { float f; unsigned u; } x; x.f = f;
    unsigned r = x.u + 0x7FFFu + ((x.u >> 16) & 1u);
    return (short)(r >> 16);
}

static __device__ __forceinline__ void gload16(const void* g, void* l) {
    __builtin_amdgcn_global_load_lds((const __attribute__((address_space(1))) void*)g,
                                     (__attribute__((address_space(3))) void*)l, 16, 0, 0);
}

// ---------- weight transpose + convert: in (K,N) f32 -> out (N,K) bf16 ----------
__global__ void convT_kernel(const float* __restrict__ in, short* __restrict__ out, int K, int N) {
    int idx = blockIdx.x * 256 + threadIdx.x;
    if (idx < K * N) {
        int k = idx % K, n = idx / K;
        out[idx] = f2bf(in[(size_t)k * N + n]);
    }
}

// ---------- bias+mask table: tab[5][64][64] ----------
__global__ void tabgen_kernel(const float* __restrict__ pos_a, const float* __restrict__ pos_b,
                              float* __restrict__ tab) {
    int v = blockIdx.x;
    const float* pos = (v == 0) ? pos_a : pos_b;
    for (int e = threadIdx.x; e < 4096; e += 256) {
        int row = e >> 6, key = e & 63;
        float val;
        if (key >= 49) val = -1e9f;
        else if (row >= 49) val = 0.f;
        else {
            int qi = row / 7, qj = row - qi * 7, ki = key / 7, kj = key - ki * 7;
            val = pos[(ki - qi + 6) * 13 + (kj - qj + 6)];
            if (v >= 1) {
                bool wh7 = (v - 1) & 2, ww7 = (v - 1) & 1;
                if (wh7 && ((qi >= 4) != (ki >= 4))) val += -1e9f;
                if (ww7 && ((qj >= 4) != (kj >= 4))) val += -1e9f;
            }
        }
        tab[v * 4096 + e] = val;
    }
}

// ---------- patch embed + LN1a: out f32 + xn bf16 ----------
__global__ __launch_bounds__(256) void patchln_kernel(const float* __restrict__ x,
                                                      const float* __restrict__ w,
                                                      const float* __restrict__ bias,
                                                      const float* __restrict__ g,
                                                      const float* __restrict__ bta,
                                                      float* __restrict__ out,
                                                      short* __restrict__ xn) {
    __shared__ float s_in[2][48];
    __shared__ float red[2][2][2];
    const int tid = threadIdx.x;
    const int half = tid >> 7, c = tid & 127;
    const int winh = (tid >> 6) & 1, lane = tid & 63;
    const int t = blockIdx.x * 2 + half;
    const int b = t / 3136, rem = t - b * 3136;
    const int hp = rem / 56, wp = rem - hp * 56;
    if (c < 48) {
        int cin = c >> 4, py = (c >> 2) & 3, px = c & 3;
        s_in[half][c] = x[((size_t)(b * 3 + cin) * 224 + hp * 4 + py) * 224 + wp * 4 + px];
    }
    __syncthreads();
    float acc = bias[c];
#pragma unroll
    for (int k = 0; k < 48; ++k) acc += s_in[half][k] * w[k * 128 + c];
    out[(size_t)t * 128 + c] = acc;
    float s1 = acc, s2 = acc * acc;
#pragma unroll
    for (int o = 32; o > 0; o >>= 1) { s1 += __shfl_xor(s1, o); s2 += __shfl_xor(s2, o); }
    if (lane == 0) { red[half][winh][0] = s1; red[half][winh][1] = s2; }
    __syncthreads();
    s1 = red[half][0][0] + red[half][1][0];
    s2 = red[half][0][1] + red[half][1][1];
    float mean = s1 * (1.f / 128.f);
    float var = s2 * (1.f / 128.f) - mean * mean;
    float rstd = rsqrtf(var + 1e-5f);
    xn[(size_t)t * 128 + c] = f2bf((acc - mean) * rstd * g[c] + bta[c]);
}

// ---------- fused window attention (48KB LDS, deferred V, merged QK proj) ----------
template <int SHIFTED>
__global__ __launch_bounds__(256, 3) void attn_kernel(const short* __restrict__ xn,
                                                      const short* __restrict__ wqkvT,
                                                      const float* __restrict__ tab,
                                                      const short* __restrict__ zpad,
                                                      short* __restrict__ aout) {
    __shared__ short smem[24576];               // 48 KB
    short* s_x = smem;                          // 64 x 256B (swizzled)
    short* s_q = smem + 8192;                   // 64 x 256B
    short* s_k = smem + 16384;                  // 64 x 256B
    short* s_vT = smem + 8192;                  // overlays s_q after dots: 128 x 128B
    short* s_p = smem + 16384;                  // overlays s_k after dots: 64 x 128B

    const int tid = threadIdx.x;
    const int wid = tid >> 6, lane = tid & 63;
    const int l15 = lane & 15, l4 = lane >> 4, klo = l4 * 8;
    const int bid = blockIdx.x;
    const int win = bid & 63, head = (bid >> 6) & 3, b = bid >> 8;
    const int wh = win >> 3, ww = win & 7;

    // ---- stage X window into swizzled s_x via global_load_lds ----
#pragma unroll
    for (int it = 0; it < 4; ++it) {
        int slot = it * 256 + tid;
        int row = slot >> 4, scol = slot & 15;
        int colb = (scol * 16) ^ ((row & 7) << 4);
        const char* g;
        if (row < 49) {
            int wi = row / 7, wj = row - wi * 7;
            int hh = wh * 7 + wi, wp = ww * 7 + wj;
            if (SHIFTED) { hh += 3; if (hh >= 56) hh -= 56; wp += 3; if (wp >= 56) wp -= 56; }
            int t = (b * 56 + hh) * 56 + wp;
            g = (const char*)(xn + (size_t)t * 128) + colb;
        } else {
            g = (const char*)zpad + colb;
        }
        gload16(g, (char*)smem + (it * 256 + wid * 64) * 16);
    }
    __syncthreads();

    const f32x4 zero4 = {0.f, 0.f, 0.f, 0.f};

    // ---- merged Q,K projection (swapped: mfma(W,X)) ----
    {
        const short* Wq = wqkvT + (size_t)(head * 128) * 128;
        const short* Wk = wqkvT + (size_t)(512 + head * 128) * 128;
        f32x4 aq[2][4], ak[2][4];
#pragma unroll
        for (int mw = 0; mw < 2; ++mw)
#pragma unroll
            for (int j = 0; j < 4; ++j) { aq[mw][j] = zero4; ak[mw][j] = zero4; }
#pragma unroll
        for (int k0 = 0; k0 < 4; ++k0) {
            bf16x8 bx[4], awq[2], awk[2];
#pragma unroll
            for (int j = 0; j < 4; ++j) {
                int row = j * 16 + l15;
                bx[j] = *(const bf16x8*)((const char*)s_x + row * 256 + ((k0 * 64 + l4 * 16) ^ ((row & 7) << 4)));
            }
#pragma unroll
            for (int mw = 0; mw < 2; ++mw) {
                awq[mw] = *(const bf16x8*)(Wq + (size_t)(wid * 32 + mw * 16 + l15) * 128 + k0 * 32 + klo);
                awk[mw] = *(const bf16x8*)(Wk + (size_t)(wid * 32 + mw * 16 + l15) * 128 + k0 * 32 + klo);
            }
            __builtin_amdgcn_s_setprio(1);
#pragma unroll
            for (int mw = 0; mw < 2; ++mw)
#pragma unroll
                for (int j = 0; j < 4; ++j) {
                    aq[mw][j] = MFMA16(awq[mw], bx[j], aq[mw][j]);
                    ak[mw][j] = MFMA16(awk[mw], bx[j], ak[mw][j]);
                }
            __builtin_amdgcn_s_setprio(0);
        }
#pragma unroll
        for (int mw = 0; mw < 2; ++mw)
#pragma unroll
            for (int j = 0; j < 4; ++j) {
                bf16x4 pq, pk;
#pragma unroll
                for (int r = 0; r < 4; ++r) { pq[r] = f2bf(aq[mw][j][r]); pk[r] = f2bf(ak[mw][j][r]); }
                int row = j * 16 + l15;
                int colb = (wid * 64 + mw * 32 + l4 * 8) ^ ((row & 7) << 4);
                *(bf16x4*)((char*)s_q + row * 256 + colb) = pq;
                *(bf16x4*)((char*)s_k + row * 256 + colb) = pk;
            }
    }
    __syncthreads();

    // ---- dots^T = mfma(K,Q): lane holds query-row qrow's 16 scores ----
    const int qrow = wid * 16 + l15;
    f32x4 dt[4];
#pragma unroll
    for (int m = 0; m < 4; ++m) dt[m] = zero4;
#pragma unroll
    for (int k0 = 0; k0 < 4; ++k0) {
        bf16x8 bq = *(const bf16x8*)((const char*)s_q + qrow * 256 + ((k0 * 64 + l4 * 16) ^ ((qrow & 7) << 4)));
        __builtin_amdgcn_s_setprio(1);
#pragma unroll
        for (int m = 0; m < 4; ++m) {
            int krow = m * 16 + l15;
            bf16x8 akf = *(const bf16x8*)((const char*)s_k + krow * 256 + ((k0 * 64 + l4 * 16) ^ ((krow & 7) << 4)));
            dt[m] = MFMA16(akf, bq, dt[m]);
        }
        __builtin_amdgcn_s_setprio(0);
    }
    __syncthreads();   // s_q/s_k now dead; safe to overlay

    // ---- in-register softmax ----
    const int variant = SHIFTED ? (1 + ((wh == 7) ? 2 : 0) + ((ww == 7) ? 1 : 0)) : 0;
    const float* tv = tab + variant * 4096 + qrow * 64;
    const float SC = 0.08838834764831845f;
    float p[4][4];
    float mx = -3.0e38f;
#pragma unroll
    for (int m = 0; m < 4; ++m) {
        f32x4 tb = *(const f32x4*)(tv + m * 16 + l4 * 4);
#pragma unroll
        for (int r = 0; r < 4; ++r) {
            float d = dt[m][r] * SC + tb[r];
            p[m][r] = d;
            mx = fmaxf(mx, d);
        }
    }
    mx = fmaxf(mx, __shfl_xor(mx, 16));
    mx = fmaxf(mx, __shfl_xor(mx, 32));
    float sum = 0.f;
#pragma unroll
    for (int m = 0; m < 4; ++m)
#pragma unroll
        for (int r = 0; r < 4; ++r) { p[m][r] = __expf(p[m][r] - mx); sum += p[m][r]; }
    sum += __shfl_xor(sum, 16);
    sum += __shfl_xor(sum, 32);
    float inv = 1.f / sum;
#pragma unroll
    for (int m = 0; m < 4; ++m) {
        bf16x4 pv;
#pragma unroll
        for (int r = 0; r < 4; ++r) pv[r] = f2bf(p[m][r] * inv);
        *(bf16x4*)((char*)s_p + qrow * 128 + ((m * 32 + l4 * 8) ^ ((qrow & 7) << 4))) = pv;
    }

    // ---- V projection (deferred; reads s_x, writes s_vT over old s_q) ----
    {
        const short* Wv = wqkvT + (size_t)(1024 + head * 128) * 128;
        f32x4 acc[4][2];
#pragma unroll
        for (int m = 0; m < 4; ++m)
#pragma unroll
            for (int n = 0; n < 2; ++n) acc[m][n] = zero4;
#pragma unroll
        for (int k0 = 0; k0 < 4; ++k0) {
            bf16x8 ax[4], bw[2];
#pragma unroll
            for (int m = 0; m < 4; ++m) {
                int row = m * 16 + l15;
                ax[m] = *(const bf16x8*)((const char*)s_x + row * 256 + ((k0 * 64 + l4 * 16) ^ ((row & 7) << 4)));
            }
#pragma unroll
            for (int n = 0; n < 2; ++n)
                bw[n] = *(const bf16x8*)(Wv + (size_t)(wid * 32 + n * 16 + l15) * 128 + k0 * 32 + klo);
            __builtin_amdgcn_s_setprio(1);
#pragma unroll
            for (int m = 0; m < 4; ++m)
#pragma unroll
                for (int n = 0; n < 2; ++n) acc[m][n] = MFMA16(ax[m], bw[n], acc[m][n]);
            __builtin_amdgcn_s_setprio(0);
        }
#pragma unroll
        for (int m = 0; m < 4; ++m)
#pragma unroll
            for (int n = 0; n < 2; ++n) {
                bf16x4 pv;
#pragma unroll
                for (int r = 0; r < 4; ++r) pv[r] = f2bf(acc[m][n][r]);
                int hd = wid * 32 + n * 16 + l15;
                int colb = (m * 32 + l4 * 8) ^ ((hd & 7) << 4);
                *(bf16x4*)((char*)s_vT + hd * 128 + colb) = pv;
            }
    }
    __syncthreads();

    // ---- out = P @ V ----
    f32x4 o[4][2];
#pragma unroll
    for (int m = 0; m < 4; ++m)
#pragma unroll
        for (int n = 0; n < 2; ++n) o[m][n] = zero4;
#pragma unroll
    for (int k0 = 0; k0 < 2; ++k0) {
        bf16x8 ap[4], bv[2];
#pragma unroll
        for (int m = 0; m < 4; ++m) {
            int row = m * 16 + l15;
            ap[m] = *(const bf16x8*)((const char*)s_p + row * 128 + ((k0 * 64 + l4 * 16) ^ ((row & 7) << 4)));
        }
#pragma unroll
        for (int n = 0; n < 2; ++n) {
            int hd = wid * 32 + n * 16 + l15;
            bv[n] = *(const bf16x8*)((const char*)s_vT + hd * 128 + ((k0 * 64 + l4 * 16) ^ ((hd & 7) << 4)));
        }
        __builtin_amdgcn_s_setprio(1);
#pragma unroll
        for (int m = 0; m < 4; ++m)
#pragma unroll
            for (int n = 0; n < 2; ++n) o[m][n] = MFMA16(ap[m], bv[n], o[m][n]);
        __builtin_amdgcn_s_setprio(0);
    }
#pragma unroll
    for (int m = 0; m < 4; ++m) {
#pragma unroll
        for (int r = 0; r < 4; ++r) {
            int rl = m * 16 + l4 * 4 + r;
            if (rl < 49) {
                int wi = rl / 7, wj = rl - wi * 7;
                int hh = wh * 7 + wi, wp = ww * 7 + wj;
                if (SHIFTED) { hh += 3; if (hh >= 56) hh -= 56; wp += 3; if (wp >= 56) wp -= 56; }
                size_t t = (size_t)(b * 56 + hh) * 56 + wp;
                aout[t * 512 + head * 128 + wid * 32 + l15] = f2bf(o[m][0][r]);
                aout[t * 512 + head * 128 + wid * 32 + 16 + l15] = f2bf(o[m][1][r]);
            }
        }
    }
}

// ---------- GEMM 128x128x64: MODE 0 = GELU->bf16, 1 = resid+LN (f32 out + bf16 xn), 2 = resid->f32 ----------
template <int K, int MODE>
__global__ __launch_bounds__(256, 2) void gemm2_kernel(const short* __restrict__ A,
                                                       const short* __restrict__ BT,
                                                       const float* __restrict__ bias,
                                                       const float* __restrict__ resid,
                                                       const float* __restrict__ g,
                                                       const float* __restrict__ bta,
                                                       float* __restrict__ outf,
                                                       short* __restrict__ outb,
                                                       int Ntot) {
    __shared__ char smem[32768];
    short* s_a = (short*)smem;              // 128 x 128B swizzled
    short* s_b = (short*)(smem + 16384);    // 128 x 128B swizzled
    float* red = (float*)smem;              // epilogue stats [128][4]

    const int tid = threadIdx.x, wid = tid >> 6, lane = tid & 63;
    const int wr = wid >> 1, wc = wid & 1;
    const int l15 = lane & 15, l4 = lane >> 4;
    const int m0 = blockIdx.x * 128;
    const int nb0 = blockIdx.y * 128;

    const f32x4 zero4 = {0.f, 0.f, 0.f, 0.f};
    f32x4 acc[4][4];
#pragma unroll
    for (int m = 0; m < 4; ++m)
#pragma unroll
        for (int n = 0; n < 4; ++n) acc[m][n] = zero4;

    for (int kc = 0; kc < K / 64; ++kc) {
#pragma unroll
        for (int it = 0; it < 4; ++it) {
            int slot = it * 256 + tid;
            int row = slot >> 3, scol = slot & 7;
            int colb = (scol * 16) ^ ((row & 7) << 4);
            gload16((const char*)(A + (size_t)(m0 + row) * K + kc * 64) + colb,
                    (char*)smem + (it * 256 + wid * 64) * 16);
        }
#pragma unroll
        for (int it = 0; it < 4; ++it) {
            int slot = it * 256 + tid;
            int row = slot >> 3, scol = slot & 7;
            int colb = (scol * 16) ^ ((row & 7) << 4);
            gload16((const char*)(BT + (size_t)(nb0 + row) * K + kc * 64) + colb,
                    (char*)smem + 16384 + (it * 256 + wid * 64) * 16);
        }
        __syncthreads();
#pragma unroll
        for (int ks = 0; ks < 2; ++ks) {
            bf16x8 a[4], bfr[4];
#pragma unroll
            for (int m = 0; m < 4; ++m) {
                int row = wr * 64 + m * 16 + l15;
                a[m] = *(const bf16x8*)((const char*)s_a + row * 128 + ((ks * 64 + l4 * 16) ^ ((row & 7) << 4)));
            }
#pragma unroll
            for (int n = 0; n < 4; ++n) {
                int row = wc * 64 + n * 16 + l15;
                bfr[n] = *(const bf16x8*)((const char*)s_b + row * 128 + ((ks * 64 + l4 * 16) ^ ((row & 7) << 4)));
            }
            __builtin_amdgcn_s_setprio(1);
#pragma unroll
            for (int m = 0; m < 4; ++m)
#pragma unroll
                for (int n = 0; n < 4; ++n) acc[m][n] = MFMA16(a[m], bfr[n], acc[m][n]);
            __builtin_amdgcn_s_setprio(0);
        }
        __syncthreads();
    }

    // ---- epilogue ----
    float bv[4];
#pragma unroll
    for (int n = 0; n < 4; ++n) bv[n] = bias[nb0 + wc * 64 + n * 16 + l15];

    if (MODE == 0) {
#pragma unroll
        for (int m = 0; m < 4; ++m)
#pragma unroll
            for (int r = 0; r < 4; ++r) {
                int row = m0 + wr * 64 + m * 16 + l4 * 4 + r;
#pragma unroll
                for (int n = 0; n < 4; ++n) {
                    int col = nb0 + wc * 64 + n * 16 + l15;
                    float v = acc[m][n][r] + bv[n];
                    v = 0.5f * v * (1.f + erff(v * 0.70710678118f));
                    outb[(size_t)row * Ntot + col] = f2bf(v);
                }
            }
        return;
    }

    float s1[4][4], s2[4][4];
#pragma unroll
    for (int m = 0; m < 4; ++m)
#pragma unroll
        for (int r = 0; r < 4; ++r) {
            int row = m0 + wr * 64 + m * 16 + l4 * 4 + r;
            float a1 = 0.f, a2 = 0.f;
#pragma unroll
            for (int n = 0; n < 4; ++n) {
                int col = wc * 64 + n * 16 + l15;
                float v = acc[m][n][r] + bv[n] + resid[(size_t)row * 128 + col];
                acc[m][n][r] = v;
                a1 += v; a2 += v * v;
            }
            s1[m][r] = a1; s2[m][r] = a2;
        }

    if (MODE == 1) {
        // butterfly over l15 -> per-row sums of this wave's 64 cols
#pragma unroll
        for (int m = 0; m < 4; ++m)
#pragma unroll
            for (int r = 0; r < 4; ++r) {
#pragma unroll
                for (int o = 1; o < 16; o <<= 1) {
                    s1[m][r] += __shfl_xor(s1[m][r], o);
                    s2[m][r] += __shfl_xor(s2[m][r], o);
                }
            }
        __syncthreads();  // LDS (s_a/s_b) dead -> reuse as red
#pragma unroll
        for (int m = 0; m < 4; ++m)
#pragma unroll
            for (int r = 0; r < 4; ++r) {
                if (l15 == m * 4 + r) {
                    int lrow = wr * 64 + m * 16 + l4 * 4 + r;
                    red[lrow * 4 + wc * 2] = s1[m][r];
                    red[lrow * 4 + wc * 2 + 1] = s2[m][r];
                }
            }
        __syncthreads();
    }

#pragma unroll
    for (int m = 0; m < 4; ++m)
#pragma unroll
        for (int r = 0; r < 4; ++r) {
            int lrow = wr * 64 + m * 16 + l4 * 4 + r;
            int row = m0 + lrow;
            float mean = 0.f, rstd = 0.f;
            if (MODE == 1) {
                float t1 = red[lrow * 4] + red[lrow * 4 + 2];
                float t2 = red[lrow * 4 + 1] + red[lrow * 4 + 3];
                mean = t1 * (1.f / 128.f);
                float var = t2 * (1.f / 128.f) - mean * mean;
                rstd = rsqrtf(var + 1e-5f);
            }
#pragma unroll
            for (int n = 0; n < 4; ++n) {
                int col = wc * 64 + n * 16 + l15;
                float v = acc[m][n][r];
                outf[(size_t)row * 128 + col] = v;
                if (MODE == 1)
                    outb[(size_t)row * 128 + col] = f2bf((v - mean) * rstd * g[col] + bta[col]);
            }
        }
}

extern "C" void kernel_launch(void* const* d_in, const int* in_sizes, int n_in,
                              void* d_out, int out_size, void* d_ws, size_t ws_size,
                              hipStream_t stream) {
    const float* x = (const float*)d_in[0];
    const float* w_pe = (const float*)d_in[1];
    const float* b_pe = (const float*)d_in[2];
    const float* P[24];
    for (int i = 0; i < 24; ++i) P[i] = (const float*)d_in[3 + i];
    // per layer s: [s*12+0..11] = ga1, be1, w_qkv, pos, w_o, b_o, ga2, be2, w_m1, b_m1, w_m2, b_m2

    float* out = (float*)d_out;
    const size_t TOK = 100352;

    short* xn = (short*)d_ws;          // TOK*128 bf16
    short* abuf = xn + TOK * 128;      // TOK*512 bf16
    short* wqkv = abuf + TOK * 512;    // 1536x128
    short* wo = wqkv + 196608;         // 128x512
    short* wm1 = wo + 65536;           // 512x128
    short* wm2 = wm1 + 65536;          // 128x512
    float* tab = (float*)(wm2 + 65536);  // 5*4096 f32
    short* zpad = (short*)(tab + 5 * 4096);  // 256B zeros

    hipMemsetAsync(zpad, 0, 256, stream);
    tabgen_kernel<<<5, 256, 0, stream>>>(P[3], P[15], tab);

    // patch embed + LN1a
    patchln_kernel<<<50176, 256, 0, stream>>>(x, w_pe, b_pe, P[0], P[1], out, xn);

    for (int s = 0; s < 2; ++s) {
        convT_kernel<<<768, 256, 0, stream>>>(P[s * 12 + 2], wqkv, 128, 1536);
        convT_kernel<<<256, 256, 0, stream>>>(P[s * 12 + 4], wo, 512, 128);
        convT_kernel<<<256, 256, 0, stream>>>(P[s * 12 + 8], wm1, 128, 512);
        convT_kernel<<<256, 256, 0, stream>>>(P[s * 12 + 10], wm2, 512, 128);

        if (s == 0)
            attn_kernel<0><<<8192, 256, 0, stream>>>(xn, wqkv, tab, zpad, abuf);
        else
            attn_kernel<1><<<8192, 256, 0, stream>>>(xn, wqkv, tab, zpad, abuf);

        // proj + residual + LN2 -> out f32, xn bf16
        gemm2_kernel<512, 1><<<dim3(784, 1), 256, 0, stream>>>(
            abuf, wo, P[s * 12 + 5], out, P[s * 12 + 6], P[s * 12 + 7], out, xn, 128);

        // mlp1 + GELU -> abuf bf16
        gemm2_kernel<128, 0><<<dim3(784, 4), 256, 0, stream>>>(
            xn, wm1, P[s * 12 + 9], nullptr, nullptr, nullptr, nullptr, abuf, 512);

        // mlp2 + residual (+LN1 of next layer for s==0)
        if (s == 0)
            gemm2_kernel<512, 1><<<dim3(784, 1), 256, 0, stream>>>(
                abuf, wm2, P[11], out, P[12], P[13], out, xn, 128);
        else
            gemm2_kernel<512, 2><<<dim3(784, 1), 256, 0, stream>>>(
                abuf, wm2, P[23], out, nullptr, nullptr, out, nullptr, 128);
    }
}